// Round 3
// baseline (292.284 us; speedup 1.0000x reference)
//
#include <hip/hip_runtime.h>

#define HW (1024 * 1024)
#define PLANE 8388608   // C * 128 * 128 = 512 * 16384
#define TS 32           // tile size: image split into 1024 disjoint 32x32 tiles

typedef _Float16 half4 __attribute__((ext_vector_type(4)));
typedef _Float16 half8 __attribute__((ext_vector_type(8)));
typedef float floatx4 __attribute__((ext_vector_type(4)));

// One fused tile-resident kernel.
// Per 32x32-px tile block:
//   1. worklist: which of the 512 windows overlap this tile (~13 avg)
//   2. layer-1: P[px][k] = sum_e W1[e][k]*xs[e][px] for the tile's 1024 px,
//      computed ONCE from x/sigma (tiles disjoint -> no redundancy) into LDS fp16
//   3. per window: MFMA MLP over the window∩tile rect, reading P from LDS.
// This converts the 8x window-overlap re-reads (268 MB via L3/HBM) into LDS
// traffic, and eliminates the P array + kernel A entirely.
// Reads: 28 MB (x,sigma once). Writes: 134 MB (compulsory output) = the floor.
__global__ __launch_bounds__(256) void instanseg_fused(
    const float* __restrict__ x,      // (6, 1024, 1024)
    const float* __restrict__ sigma,  // (1, 1024, 1024)
    const float* __restrict__ c,      // (512, 6)
    const float* __restrict__ W1,     // (7, 16)
    const float* __restrict__ b1,     // (16)
    const float* __restrict__ W2,     // (16, 16)
    const float* __restrict__ b2,     // (16)
    const float* __restrict__ W3,     // (16, 1)
    const float* __restrict__ b3,     // (1)
    const int*   __restrict__ cent,   // (512, 2)
    float* __restrict__ out)
{
    __shared__ _Float16 tileP[TS * TS * 16];   // 32 KB, px-major
    __shared__ int wlist[512];
    __shared__ int wcount;

    const int tid = threadIdx.x;
    const int ty = (blockIdx.x >> 5) * TS;
    const int tx = (blockIdx.x & 31) * TS;

    if (tid == 0) wcount = 0;
    __syncthreads();

    // ---- 1. worklist: overlap test for all 512 windows ----
    for (int w = tid; w < 512; w += 256) {
        const int cy = min(max(cent[2 * w], 64), 960);
        const int cx = min(max(cent[2 * w + 1], 64), 960);
        const int cy0 = cy - 64, cx0 = cx - 64;
        if (cy0 < ty + TS && cy0 + 128 > ty && cx0 < tx + TS && cx0 + 128 > tx)
            wlist[atomicAdd(&wcount, 1)] = w;
    }
    __syncthreads();
    const int nw = wcount;
    if (nw == 0) return;   // whole-block exit: no divergence hazard

    // ---- 2. fused layer-1 for this tile's 1024 px (bit-identical to old kernel A) ----
#pragma unroll
    for (int pass = 0; pass < 4; ++pass) {
        const int p = pass * 256 + tid;
        const int gpx = (ty + (p >> 5)) * 1024 + tx + (p & 31);   // 128B-coalesced rows
        float g[7];
#pragma unroll
        for (int e = 0; e < 6; ++e) g[e] = x[e * HW + gpx];
        g[6] = sigma[gpx];
        half8 lo, hi;
#pragma unroll
        for (int j = 0; j < 16; ++j) {
            float a = 0.0f;
#pragma unroll
            for (int e = 0; e < 7; ++e)
                a = fmaf(g[e], W1[e * 16 + j], a);
            if (j < 8) lo[j] = (_Float16)a; else hi[j - 8] = (_Float16)a;
        }
        *(half8*)&tileP[p * 16]     = lo;
        *(half8*)&tileP[p * 16 + 8] = hi;
    }
    __syncthreads();

    const int lane = tid & 63, wave = tid >> 6;
    const int quad = lane >> 4, sub = lane & 15;

    // window-independent layer-2/3 fragments (same layout as verified kernel)
    half4 a2;
    float w3f[4], bb2[4];
#pragma unroll
    for (int i = 0; i < 4; ++i) {
        const int k = 4 * quad + i;
        a2[i]  = (_Float16)W2[k * 16 + sub];
        w3f[i] = W3[k];
        bb2[i] = b2[k];
    }
    const float b3v = b3[0];
    const floatx4 zero = {0.0f, 0.0f, 0.0f, 0.0f};

    // ---- 3. per overlapping window: MLP on the intersection rect ----
    for (int wi = 0; wi < nw; ++wi) {
        const int cid = wlist[wi];
        const int cy = min(max(cent[2 * cid], 64), 960);
        const int cx = min(max(cent[2 * cid + 1], 64), 960);
        const int cy0 = cy - 64, cx0 = cx - 64;

        half4 qh;   // q[k] = sum_e W1[e][k]*c[cid][e] - b1[k], k = 4*quad+i
#pragma unroll
        for (int i = 0; i < 4; ++i) {
            const int k = 4 * quad + i;
            float qv = -b1[k];
#pragma unroll
            for (int e = 0; e < 6; ++e)
                qv = fmaf(W1[e * 16 + k], c[cid * 6 + e], qv);
            qh[i] = (_Float16)qv;
        }

        // rect in tile-local coords (strict overlap -> r0<r1, c0<c1)
        const int r0 = max(cy0 - ty, 0), r1 = min(cy0 + 128 - ty, TS);
        const int c0 = max(cx0 - tx, 0), c1 = min(cx0 + 128 - tx, TS);
        const int c0a  = c0 & ~15;                 // 16-aligned segment origin (0 or 16)
        const int segw = (c1 - c0a + 15) >> 4;     // 1 or 2 (TS=32 guarantees <=2)
        const int rpi  = (segw == 2) ? 2 : 4;      // rows per wave-iter

        // 4 waves stripe the rect rows; 4 fragments/iter = (rpi rows) x (segw segs)
        for (int rb = r0 + wave * rpi; rb < r1; rb += rpi * 4) {
            float logit[4];
#pragma unroll
            for (int ch = 0; ch < 4; ++ch) {
                const int dr  = (segw == 2) ? (ch >> 1) : ch;
                const int cs  = (segw == 2) ? (ch & 1) : 0;
                const int row = rb + dr;
                const int rc  = min(row, TS - 1);          // clamp: masked at store
                const int lc  = c0a + cs * 16 + sub;       // < 32 by construction
                half4 v = *(const half4*)&tileP[(rc * TS + lc) * 16 + quad * 4];
                half4 h = v - qh;                          // v_pk_add_f16
#pragma unroll
                for (int i = 0; i < 4; ++i)                // relu
                    h[i] = h[i] > (_Float16)0.0f ? h[i] : (_Float16)0.0f;

                floatx4 c2 = __builtin_amdgcn_mfma_f32_16x16x16f16(a2, h, zero, 0, 0, 0);

                float part = 0.0f;
#pragma unroll
                for (int i = 0; i < 4; ++i)
                    part = fmaf(w3f[i], fmaxf(c2[i] + bb2[i], 0.0f), part);
                part += __shfl_xor(part, 16, 64);
                part += __shfl_xor(part, 32, 64);
                logit[ch] = part;   // full 16-sum for px (frag ch, col sub); MFMA
            }                       // columns are independent -> garbage cols safe

            const float l01 = (quad & 1) ? logit[1] : logit[0];
            const float l23 = (quad & 1) ? logit[3] : logit[2];
            const float lg  = (quad & 2) ? l23 : l01;      // = logit[quad]

            // this lane's output px: fragment quad, column sub
            const int dr_l  = (segw == 2) ? (quad >> 1) : quad;
            const int cs_l  = (segw == 2) ? (quad & 1) : 0;
            const int row_l = rb + dr_l;
            const int lc_l  = c0a + cs_l * 16 + sub;
            if (row_l < r1 && lc_l >= c0 && lc_l < c1) {
                const float prob = 1.0f / (1.0f + __expf(-(lg + b3v)));
                const int iy = ty + row_l, ix = tx + lc_l;
                const int n  = cid * 16384 + (iy - cy0) * 128 + (ix - cx0);
                __builtin_nontemporal_store(prob,        out + n);
                __builtin_nontemporal_store((float)cid,  out + PLANE + n);
                __builtin_nontemporal_store((float)iy,   out + 2 * PLANE + n);
                __builtin_nontemporal_store((float)ix,   out + 3 * PLANE + n);
            }
        }
    }
}

extern "C" void kernel_launch(void* const* d_in, const int* in_sizes, int n_in,
                              void* d_out, int out_size, void* d_ws, size_t ws_size,
                              hipStream_t stream) {
    const float* x     = (const float*)d_in[0];
    const float* sigma = (const float*)d_in[1];
    const float* c     = (const float*)d_in[2];
    const float* W1    = (const float*)d_in[3];
    const float* b1    = (const float*)d_in[4];
    const float* W2    = (const float*)d_in[5];
    const float* b2    = (const float*)d_in[6];
    const float* W3    = (const float*)d_in[7];
    const float* b3    = (const float*)d_in[8];
    const int*   cent  = (const int*)d_in[9];
    float* out = (float*)d_out;
    (void)d_ws; (void)ws_size;   // workspace no longer needed

    instanseg_fused<<<dim3(1024), dim3(256), 0, stream>>>(
        x, sigma, c, W1, b1, W2, b2, W3, b3, cent, out);
}

// Round 4
// 225.406 us; speedup vs baseline: 1.2967x; 1.2967x over previous
//
#include <hip/hip_runtime.h>

#define WS 128
#define HW (1024 * 1024)
#define PLANE 8388608   // C * WS * WS = 512 * 16384
#define PERM_BYTE_OFF 33554432   // perm[] lives after the 32 MB P array in ws

typedef _Float16 half4 __attribute__((ext_vector_type(4)));
typedef _Float16 half8 __attribute__((ext_vector_type(8)));
typedef float floatx4 __attribute__((ext_vector_type(4)));

__device__ inline unsigned part1by1(unsigned v) {
    v &= 0x0000ffff;
    v = (v ^ (v << 8)) & 0x00ff00ff;
    v = (v ^ (v << 4)) & 0x0f0f0f0f;
    v = (v ^ (v << 2)) & 0x33333333;
    v = (v ^ (v << 1)) & 0x55555555;
    return v;
}

// Kernel A: P[src][j] = sum_e W1[e][j] * xs[e][src]  (window-independent layer-1),
// px-major fp16 so kernel B's B-fragment load is one 8B half4.
// Block 4096: Morton rank-sort of the 512 clamped centres -> perm[] (bijective).
__global__ __launch_bounds__(256) void precompute_P(
    const float* __restrict__ x,      // (6, 1024, 1024)
    const float* __restrict__ sigma,  // (1, 1024, 1024)
    const float* __restrict__ W1,     // (7, 16)
    const int*   __restrict__ cent,   // (512, 2)
    _Float16* __restrict__ P,         // (1024*1024, 16)
    int* __restrict__ perm)           // (512)
{
    if (blockIdx.x == 4096) {
        __shared__ unsigned keys[512];
        const int t = threadIdx.x;
        for (int i = t; i < 512; i += 256) {
            const unsigned cy = (unsigned)min(max(cent[2 * i], 64), 960);
            const unsigned cx = (unsigned)min(max(cent[2 * i + 1], 64), 960);
            keys[i] = (part1by1(cy) << 1) | part1by1(cx);
        }
        __syncthreads();
        for (int i = t; i < 512; i += 256) {
            const unsigned ki = keys[i];
            int r = 0;
            for (int j = 0; j < 512; ++j) {
                const unsigned kj = keys[j];
                r += (kj < ki || (kj == ki && j < i)) ? 1 : 0;
            }
            perm[r] = i;   // every rank hit exactly once
        }
        return;
    }

    const int px = blockIdx.x * 256 + threadIdx.x;
    float g[7];
#pragma unroll
    for (int e = 0; e < 6; ++e) g[e] = x[e * HW + px];
    g[6] = sigma[px];

    half8 lo, hi;
#pragma unroll
    for (int j = 0; j < 16; ++j) {
        float a = 0.0f;
#pragma unroll
        for (int e = 0; e < 7; ++e)
            a = fmaf(g[e], W1[e * 16 + j], a);
        if (j < 8) lo[j] = (_Float16)a; else hi[j - 8] = (_Float16)a;
    }
    *(half8*)(P + (size_t)px * 16)     = lo;
    *(half8*)(P + (size_t)px * 16 + 8) = hi;
}

// Kernel B (R2-verified inner loop). Round-4 change is ONLY the work->block
// mapping: 1024 blocks, one HALF-window each.  XCD g (= lid&7 under the HW's
// round-robin block->XCD dispatch) owns Morton ranks [64g, 64g+64): its 64
// windows tile ~1/8 of the image ~= 4 MB ~= its private L2, and the NT output
// stores (kept from R2) no longer evict it.  Both conditions must hold at once:
// R1 had the banding but cache-thrashing writes; R2 had NT writes but an
// all-XCDs-see-all-windows grid.  Each alone measured null.
__global__ __launch_bounds__(256) void instanseg_mlp(
    const _Float16* __restrict__ P,   // (1024*1024, 16)
    const float* __restrict__ c,      // (512, 6)
    const float* __restrict__ W1,     // (7, 16)
    const float* __restrict__ b1,     // (16)
    const float* __restrict__ W2,     // (16, 16)
    const float* __restrict__ b2,     // (16)
    const float* __restrict__ W3,     // (16, 1)
    const float* __restrict__ b3,     // (1)
    const int*   __restrict__ cent,   // (512, 2)
    const int*   __restrict__ perm,   // (512) Morton rank -> cid
    float* __restrict__ out)
{
    const int lid  = blockIdx.x;
    const int g    = lid & 7;                 // XCD under lid%8 round-robin
    const int j    = lid >> 3;                // [0,128) within XCD
    const int rank = g * 64 + (j >> 1);       // Morton band per XCD
    const int half = j & 1;                   // top/bottom half-window
    const int cid  = perm[rank];

    const int lane = threadIdx.x & 63;
    const int wave = threadIdx.x >> 6;
    const int quad = lane >> 4;
    const int sub  = lane & 15;

    const int cy = min(max(cent[2 * cid], 64), 960);
    const int cx = min(max(cent[2 * cid + 1], 64), 960);
    const int cy0 = cy - 64, cx0 = cx - 64;

    // A-fragment for layer 2: A[m=sub][k=4*quad+i] = W2[k][m]
    half4 a2;
    float w3f[4], bb2[4];
    half4 qh;   // q[k] = sum_{e<6} W1[e][k]*c[cid][e] - b1[k], k = 4*quad+i
#pragma unroll
    for (int i = 0; i < 4; ++i) {
        const int k = 4 * quad + i;
        a2[i]  = (_Float16)W2[k * 16 + sub];
        w3f[i] = W3[k];
        bb2[i] = b2[k];
        float qv = -b1[k];
#pragma unroll
        for (int e = 0; e < 6; ++e)
            qv = fmaf(W1[e * 16 + k], c[cid * 6 + e], qv);
        qh[i] = (_Float16)qv;
    }
    const float b3v = b3[0];
    const floatx4 zero = {0.0f, 0.0f, 0.0f, 0.0f};

    // this block: half-window px [half*8192, +8192); this wave: 2048 px
    const int wavestart = half * 8192 + wave * 2048;

    // ---- 2-stage pipelined gather + compute over 32 wave-iterations ----
    half4 v[4], vn[4];
    {
        const int base = (cy0 + (wavestart >> 7)) * 1024 + cx0 + sub;
        const _Float16* rowp = P + (size_t)base * 16 + quad * 4;
#pragma unroll
        for (int ch = 0; ch < 4; ++ch)
            v[ch] = *(const half4*)(rowp + ch * 256);   // 16 px * 32B = 512 B
    }

    for (int it = 0; it < 32; ++it) {
        const int start = wavestart + it * 64;

        if (it < 31) {   // batch-issue next iteration's 4 gathers
            const int nstart = start + 64;
            const int base = (cy0 + (nstart >> 7)) * 1024 + cx0 + (nstart & 127) + sub;
            const _Float16* rowp = P + (size_t)base * 16 + quad * 4;
#pragma unroll
            for (int ch = 0; ch < 4; ++ch)
                vn[ch] = *(const half4*)(rowp + ch * 256);
        }

        float logit[4];
#pragma unroll
        for (int ch = 0; ch < 4; ++ch) {
            half4 h = v[ch] - qh;                       // v_pk_add_f16
#pragma unroll
            for (int i = 0; i < 4; ++i)                 // relu -> v_pk_max_f16
                h[i] = h[i] > (_Float16)0.0f ? h[i] : (_Float16)0.0f;

            floatx4 c2 = __builtin_amdgcn_mfma_f32_16x16x16f16(a2, h, zero, 0, 0, 0);

            float part = 0.0f;
#pragma unroll
            for (int i = 0; i < 4; ++i)
                part = fmaf(w3f[i], fmaxf(c2[i] + bb2[i], 0.0f), part);
            part += __shfl_xor(part, 16, 64);
            part += __shfl_xor(part, 32, 64);
            logit[ch] = part;
        }

        const float l01 = (quad & 1) ? logit[1] : logit[0];
        const float l23 = (quad & 1) ? logit[3] : logit[2];
        const float lg  = (quad & 2) ? l23 : l01;
        const float prob = 1.0f / (1.0f + __expf(-(lg + b3v)));

        const int rowy = cy0 + (start >> 7);            // wave-uniform
        const int colx = cx0 + (start & 127) + lane;
        const int n    = cid * 16384 + start + lane;
        __builtin_nontemporal_store(prob,        out + n);
        __builtin_nontemporal_store((float)cid,  out + PLANE + n);
        __builtin_nontemporal_store((float)rowy, out + 2 * PLANE + n);
        __builtin_nontemporal_store((float)colx, out + 3 * PLANE + n);

        if (it < 31) {
#pragma unroll
            for (int ch = 0; ch < 4; ++ch) v[ch] = vn[ch];
        }
    }
}

extern "C" void kernel_launch(void* const* d_in, const int* in_sizes, int n_in,
                              void* d_out, int out_size, void* d_ws, size_t ws_size,
                              hipStream_t stream) {
    const float* x     = (const float*)d_in[0];
    const float* sigma = (const float*)d_in[1];
    const float* c     = (const float*)d_in[2];
    const float* W1    = (const float*)d_in[3];
    const float* b1    = (const float*)d_in[4];
    const float* W2    = (const float*)d_in[5];
    const float* b2    = (const float*)d_in[6];
    const float* W3    = (const float*)d_in[7];
    const float* b3    = (const float*)d_in[8];
    const int*   cent  = (const int*)d_in[9];
    float* out = (float*)d_out;
    _Float16* P = (_Float16*)d_ws;                      // 32 MB fp16 scratch
    int* perm   = (int*)((char*)d_ws + PERM_BYTE_OFF);  // 2 KB after P

    precompute_P<<<dim3(4097), dim3(256), 0, stream>>>(x, sigma, W1, cent, P, perm);
    instanseg_mlp<<<dim3(1024), dim3(256), 0, stream>>>(
        P, c, W1, b1, W2, b2, W3, b3, cent, perm, out);
}

// Round 5
// 200.971 us; speedup vs baseline: 1.4544x; 1.1216x over previous
//
#include <hip/hip_runtime.h>

#define WS 128
#define HW (1024 * 1024)
#define PLANE 8388608   // C * WS * WS = 512 * 16384

typedef _Float16 half4 __attribute__((ext_vector_type(4)));
typedef _Float16 half8 __attribute__((ext_vector_type(8)));
typedef float floatx4 __attribute__((ext_vector_type(4)));

// Kernel A: G[px][e] = fp16(xs[e][px]) for e<7, 0 pad at e=7.  16 B/px.
// (Round-5: we no longer precompute layer-1's 16 channels (32 B/px); layer-1
// moved into kernel B as an extra MFMA, halving B's gather bytes — the
// cross-round accounting shows B runs at ~5.5 TB/s effective, i.e. it is
// fabric-BYTE-limited, so bytes are the only lever.)
__global__ __launch_bounds__(256) void precompute_G(
    const float* __restrict__ x,      // (6, 1024, 1024)
    const float* __restrict__ sigma,  // (1, 1024, 1024)
    _Float16* __restrict__ G)         // (1024*1024, 8)
{
    const int px = blockIdx.x * 256 + threadIdx.x;
    half8 g;
#pragma unroll
    for (int e = 0; e < 6; ++e) g[e] = (_Float16)x[e * HW + px];
    g[6] = (_Float16)sigma[px];
    g[7] = (_Float16)0.0f;
    *(half8*)(G + (size_t)px * 8) = g;
}

// Kernel B: per window-pixel, on the matrix pipe:
//   c1 = W1^T g          (MFMA1, K=16 zero-padded from 7)
//   h  = relu(c1 - q)    (f32 epilogue of MFMA1; q = W1^T c[cid] - ... + b1 fold)
//   c2 = W2^T h          (MFMA2)
//   prob = sigmoid(W3 . relu(c2 + b2) + b3)
// Structural identity that makes this free of shuffles: MFMA 16x16x16 C-layout
// (row 4q+i, col sub) == the B-fragment layout (k=4q+i, n=sub) MFMA2 consumes.
// Grid/stores are the best-measured R0 structure, unchanged.
__global__ __launch_bounds__(256) void instanseg_mlp(
    const _Float16* __restrict__ G,   // (1024*1024, 8)
    const float* __restrict__ c,      // (512, 6)
    const float* __restrict__ W1,     // (7, 16)
    const float* __restrict__ b1,     // (16)
    const float* __restrict__ W2,     // (16, 16)
    const float* __restrict__ b2,     // (16)
    const float* __restrict__ W3,     // (16, 1)
    const float* __restrict__ b3,     // (1)
    const int*   __restrict__ cent,   // (512, 2)
    float* __restrict__ out)
{
    const int cid  = blockIdx.y;
    const int lane = threadIdx.x & 63;
    const int wave = threadIdx.x >> 6;
    const int quad = lane >> 4;
    const int sub  = lane & 15;

    const int cy = min(max(cent[2 * cid], 64), 960);
    const int cx = min(max(cent[2 * cid + 1], 64), 960);
    const int cy0 = cy - 64, cx0 = cx - 64;

    // MFMA1 A-fragment: A[m=sub][k=4*quad+i] = W1[k][sub] (0 for k >= 7)
    half4 a1;
#pragma unroll
    for (int i = 0; i < 4; ++i) {
        const int k = 4 * quad + i;
        a1[i] = (k < 7) ? (_Float16)W1[k * 16 + sub] : (_Float16)0.0f;
    }

    // MFMA2 A-fragment + f32 layer-1 offset q and layer-2/3 constants
    half4 a2;
    float w3f[4], bb2[4], qf[4];
#pragma unroll
    for (int i = 0; i < 4; ++i) {
        const int k = 4 * quad + i;
        a2[i]  = (_Float16)W2[k * 16 + sub];
        w3f[i] = W3[k];
        bb2[i] = b2[k];
        float qv = -b1[k];
#pragma unroll
        for (int e = 0; e < 6; ++e)
            qv = fmaf(W1[e * 16 + k], c[cid * 6 + e], qv);
        qf[i] = qv;
    }
    const float b3v = b3[0];
    const floatx4 zero = {0.0f, 0.0f, 0.0f, 0.0f};

    const int wavestart = blockIdx.x * 2048 + wave * 512;

    for (int it = 0; it < 8; ++it) {
        const int start = wavestart + it * 64;
        float logit[4];
#pragma unroll
        for (int ch = 0; ch < 4; ++ch) {
            const int gp  = start + ch * 16 + sub;
            const int src = (cy0 + (gp >> 7)) * 1024 + cx0 + (gp & 127);

            // B-fragment of g: k = 4*quad..4*quad+3 of pixel sub.
            // Only quads 0,1 carry real channels (k<8): 256 B per fragment.
            half4 bg = {};
            if (quad < 2)
                bg = *(const half4*)(G + (size_t)src * 8 + quad * 4);

            // layer 1 on the matrix pipe
            floatx4 c1 = __builtin_amdgcn_mfma_f32_16x16x16f16(a1, bg, zero, 0, 0, 0);

            // h = relu(c1 - q), single fp16 rounding (RNE) — C-layout == B-layout
            half4 h;
#pragma unroll
            for (int i = 0; i < 4; ++i)
                h[i] = (_Float16)fmaxf(c1[i] - qf[i], 0.0f);

            // layer 2 on the matrix pipe
            floatx4 c2 = __builtin_amdgcn_mfma_f32_16x16x16f16(a2, h, zero, 0, 0, 0);

            float part = 0.0f;
#pragma unroll
            for (int i = 0; i < 4; ++i)
                part = fmaf(w3f[i], fmaxf(c2[i] + bb2[i], 0.0f), part);
            part += __shfl_xor(part, 16, 64);
            part += __shfl_xor(part, 32, 64);
            logit[ch] = part;
        }

        const float l01 = (quad & 1) ? logit[1] : logit[0];
        const float l23 = (quad & 1) ? logit[3] : logit[2];
        const float lg  = (quad & 2) ? l23 : l01;
        const float prob = 1.0f / (1.0f + __expf(-(lg + b3v)));

        const int gps = start + lane;
        const int n   = cid * 16384 + gps;
        out[n]             = prob;
        out[PLANE + n]     = (float)cid;
        out[2 * PLANE + n] = (float)(cy0 + (gps >> 7));
        out[3 * PLANE + n] = (float)(cx0 + (gps & 127));
    }
}

extern "C" void kernel_launch(void* const* d_in, const int* in_sizes, int n_in,
                              void* d_out, int out_size, void* d_ws, size_t ws_size,
                              hipStream_t stream) {
    const float* x     = (const float*)d_in[0];
    const float* sigma = (const float*)d_in[1];
    const float* c     = (const float*)d_in[2];
    const float* W1    = (const float*)d_in[3];
    const float* b1    = (const float*)d_in[4];
    const float* W2    = (const float*)d_in[5];
    const float* b2    = (const float*)d_in[6];
    const float* W3    = (const float*)d_in[7];
    const float* b3    = (const float*)d_in[8];
    const int*   cent  = (const int*)d_in[9];
    float* out = (float*)d_out;
    _Float16* G = (_Float16*)d_ws;   // 1024*1024*8 fp16 = 16 MB scratch

    precompute_G<<<dim3(HW / 256), dim3(256), 0, stream>>>(x, sigma, G);
    instanseg_mlp<<<dim3(8, 512), dim3(256), 0, stream>>>(
        G, c, W1, b1, W2, b2, W3, b3, cent, out);
}

// Round 7
// 192.697 us; speedup vs baseline: 1.5168x; 1.0429x over previous
//
#include <hip/hip_runtime.h>

#define WS 128
#define HW (1024 * 1024)
#define PLANE 8388608   // C * WS * WS = 512 * 16384

typedef _Float16 half4 __attribute__((ext_vector_type(4)));
typedef _Float16 half8 __attribute__((ext_vector_type(8)));
typedef float floatx4 __attribute__((ext_vector_type(4)));

// Kernel A: G[px][e] = fp16(xs[e][px]) for e<7, 0 pad at e=7.  16 B/px.
__global__ __launch_bounds__(256) void precompute_G(
    const float* __restrict__ x,      // (6, 1024, 1024)
    const float* __restrict__ sigma,  // (1, 1024, 1024)
    _Float16* __restrict__ G)         // (1024*1024, 8)
{
    const int px = blockIdx.x * 256 + threadIdx.x;
    half8 g;
#pragma unroll
    for (int e = 0; e < 6; ++e) g[e] = (_Float16)x[e * HW + px];
    g[6] = (_Float16)sigma[px];
    g[7] = (_Float16)0.0f;
    *(half8*)(G + (size_t)px * 8) = g;
}

// Kernel B (R5 two-MFMA structure + R2 2-stage pipeline).
//   c1 = W1^T g   (MFMA1, K zero-padded 7->16)
//   h  = relu(c1 - q)          [C-layout == B-fragment layout: no shuffle]
//   c2 = W2^T h   (MFMA2);  prob = sigmoid(W3 . relu(c2+b2) + b3)
// Batch-issue the next iteration's 4 G-fragment loads (quads 0-1) before
// computing the current one.  R2 measured this null — but that was the
// byte-bound regime (268 MB reads); after R5's byte cut B runs at 4 TB/s
// effective, i.e. latency-exposed, so the prefetch now has something to hide.
// Row-base addressing: each wave-iter's 64 px are one contiguous row segment.
// NOTE: the quad<2 guard is semantically required — MFMA1's B-fragment rows
// k>=8 must be zero (G has only 8 channels), so quads 2-3 keep v[ch]=0.
__global__ __launch_bounds__(256) void instanseg_mlp(
    const _Float16* __restrict__ G,   // (1024*1024, 8)
    const float* __restrict__ c,      // (512, 6)
    const float* __restrict__ W1,     // (7, 16)
    const float* __restrict__ b1,     // (16)
    const float* __restrict__ W2,     // (16, 16)
    const float* __restrict__ b2,     // (16)
    const float* __restrict__ W3,     // (16, 1)
    const float* __restrict__ b3,     // (1)
    const int*   __restrict__ cent,   // (512, 2)
    float* __restrict__ out)
{
    const int cid  = blockIdx.y;
    const int lane = threadIdx.x & 63;
    const int wave = threadIdx.x >> 6;
    const int quad = lane >> 4;
    const int sub  = lane & 15;

    const int cy = min(max(cent[2 * cid], 64), 960);
    const int cx = min(max(cent[2 * cid + 1], 64), 960);
    const int cy0 = cy - 64, cx0 = cx - 64;

    // MFMA1 A-fragment: A[m=sub][k=4*quad+i] = W1[k][sub] (0 for k >= 7)
    half4 a1;
#pragma unroll
    for (int i = 0; i < 4; ++i) {
        const int k = 4 * quad + i;
        a1[i] = (k < 7) ? (_Float16)W1[k * 16 + sub] : (_Float16)0.0f;
    }

    // MFMA2 A-fragment + f32 layer-1 offset q and layer-2/3 constants
    half4 a2;
    float w3f[4], bb2[4], qf[4];
#pragma unroll
    for (int i = 0; i < 4; ++i) {
        const int k = 4 * quad + i;
        a2[i]  = (_Float16)W2[k * 16 + sub];
        w3f[i] = W3[k];
        bb2[i] = b2[k];
        float qv = -b1[k];
#pragma unroll
        for (int e = 0; e < 6; ++e)
            qv = fmaf(W1[e * 16 + k], c[cid * 6 + e], qv);
        qf[i] = qv;
    }
    const float b3v = b3[0];
    const floatx4 zero = {0.0f, 0.0f, 0.0f, 0.0f};

    const int wavestart = blockIdx.x * 2048 + wave * 512;

    // ---- 2-stage pipelined gather (quads 0-1 carry data; 2-3 stay zero,
    //      required: MFMA1 B-fragment rows k>=8 are zero) ----
    half4 v[4], vn[4];
#pragma unroll
    for (int ch = 0; ch < 4; ++ch) { v[ch] = (half4)(_Float16)0.0f; vn[ch] = (half4)(_Float16)0.0f; }
    {
        // wavestart % 512 == 0 -> (wavestart & 127) == 0: one row segment
        const int base = (cy0 + (wavestart >> 7)) * 1024 + cx0 + sub;
        const _Float16* rowp = G + (size_t)base * 8 + quad * 4;
        if (quad < 2) {
#pragma unroll
            for (int ch = 0; ch < 4; ++ch)
                v[ch] = *(const half4*)(rowp + ch * 128);   // 16 px * 8 ch
        }
    }

    for (int it = 0; it < 8; ++it) {
        const int start = wavestart + it * 64;

        if (it < 7) {   // batch-issue next iteration's 4 fragment loads
            const int nstart = start + 64;
            const int base = (cy0 + (nstart >> 7)) * 1024 + cx0 + (nstart & 127) + sub;
            const _Float16* rowp = G + (size_t)base * 8 + quad * 4;
            if (quad < 2) {
#pragma unroll
                for (int ch = 0; ch < 4; ++ch)
                    vn[ch] = *(const half4*)(rowp + ch * 128);
            }
        }

        float logit[4];
#pragma unroll
        for (int ch = 0; ch < 4; ++ch) {
            // layer 1 on the matrix pipe
            floatx4 c1 = __builtin_amdgcn_mfma_f32_16x16x16f16(a1, v[ch], zero, 0, 0, 0);

            // h = relu(c1 - q), single fp16 rounding — C-layout == B-layout
            half4 h;
#pragma unroll
            for (int i = 0; i < 4; ++i)
                h[i] = (_Float16)fmaxf(c1[i] - qf[i], 0.0f);

            // layer 2 on the matrix pipe
            floatx4 c2 = __builtin_amdgcn_mfma_f32_16x16x16f16(a2, h, zero, 0, 0, 0);

            float part = 0.0f;
#pragma unroll
            for (int i = 0; i < 4; ++i)
                part = fmaf(w3f[i], fmaxf(c2[i] + bb2[i], 0.0f), part);
            part += __shfl_xor(part, 16, 64);
            part += __shfl_xor(part, 32, 64);
            logit[ch] = part;
        }

        const float l01 = (quad & 1) ? logit[1] : logit[0];
        const float l23 = (quad & 1) ? logit[3] : logit[2];
        const float lg  = (quad & 2) ? l23 : l01;
        const float prob = 1.0f / (1.0f + __expf(-(lg + b3v)));

        const int rowy = cy0 + (start >> 7);            // wave-uniform
        const int colx = cx0 + (start & 127) + lane;
        const int n    = cid * 16384 + start + lane;
        out[n]             = prob;
        out[PLANE + n]     = (float)cid;
        out[2 * PLANE + n] = (float)rowy;
        out[3 * PLANE + n] = (float)colx;

        if (it < 7) {
#pragma unroll
            for (int ch = 0; ch < 4; ++ch) v[ch] = vn[ch];
        }
    }
}

extern "C" void kernel_launch(void* const* d_in, const int* in_sizes, int n_in,
                              void* d_out, int out_size, void* d_ws, size_t ws_size,
                              hipStream_t stream) {
    const float* x     = (const float*)d_in[0];
    const float* sigma = (const float*)d_in[1];
    const float* c     = (const float*)d_in[2];
    const float* W1    = (const float*)d_in[3];
    const float* b1    = (const float*)d_in[4];
    const float* W2    = (const float*)d_in[5];
    const float* b2    = (const float*)d_in[6];
    const float* W3    = (const float*)d_in[7];
    const float* b3    = (const float*)d_in[8];
    const int*   cent  = (const int*)d_in[9];
    float* out = (float*)d_out;
    _Float16* G = (_Float16*)d_ws;   // 1024*1024*8 fp16 = 16 MB scratch

    precompute_G<<<dim3(HW / 256), dim3(256), 0, stream>>>(x, sigma, G);
    instanseg_mlp<<<dim3(8, 512), dim3(256), 0, stream>>>(
        G, c, W1, b1, W2, b2, W3, b3, cent, out);
}